// Round 12
// baseline (1748.410 us; speedup 1.0000x reference)
//
#include <hip/hip_runtime.h>
#include <hip/hip_bf16.h>
#include <math.h>

#define CD 128
#define HH 4
#define DH 32
#define LL 2

using bf16 = __hip_bfloat16;
using bf16x8 = __attribute__((ext_vector_type(8))) short;  // 8 bf16 (4 VGPRs)
using f32x4 = __attribute__((ext_vector_type(4))) float;

__device__ __forceinline__ float bfbits2f(unsigned int s) {
  return __uint_as_float(s << 16);
}

__device__ __forceinline__ unsigned short f2bfbits(float f) {
  unsigned int u = __float_as_uint(f);
  unsigned int r = (u + 0x7fff + ((u >> 16) & 1)) >> 16;  // RNE
  return (unsigned short)r;
}

__device__ __forceinline__ float gelu_f(float x) {
  return 0.5f * x * (1.0f + erff(x * 0.70710678118654752f));
}

// ---- detect input formats: flags[0]=floats-are-f32, flags[1]=edge-index-is-i64 ----
__global__ void k_detect(const void* __restrict__ x, const int* __restrict__ ei,
                         int* __restrict__ flags) {
  __shared__ int cnt_f32, cnt_i32;
  if (threadIdx.x == 0) { cnt_f32 = 0; cnt_i32 = 0; }
  __syncthreads();
  int t = threadIdx.x;  // 128 threads
  unsigned short u = ((const unsigned short*)x)[2 * t];
  float v = bfbits2f((unsigned int)u);
  float av = fabsf(v);
  if (av != 0.f && (av > 1e8f || av < 1e-8f)) atomicAdd(&cnt_f32, 1);
  if (t < 64) {
    if (((const int*)ei)[2 * t + 1] != 0) atomicAdd(&cnt_i32, 1);
  }
  __syncthreads();
  if (threadIdx.x == 0) {
    flags[0] = (cnt_f32 > 8) ? 1 : 0;
    flags[1] = (cnt_i32 == 0) ? 1 : 0;
  }
}

// ---- x -> f32 hbuf AND bf16 hbuf16 ----
__global__ void k_cvt_x(const void* __restrict__ in, float* __restrict__ out,
                        unsigned short* __restrict__ out16, int n,
                        const int* __restrict__ flags) {
  int i = blockIdx.x * blockDim.x + threadIdx.x;
  if (i >= n) return;
  float v = flags[0] ? ((const float*)in)[i]
                     : bfbits2f((unsigned int)((const unsigned short*)in)[i]);
  out[i] = v;
  out16[i] = f2bfbits(v);
}

// ---- all parameter tensors -> contiguous f32 block, one launch ----
#define NSEG 14
struct SegTab {
  const void* src[NSEG];
  int off[NSEG];
  int total;
};
__global__ void k_cvt_params(SegTab tab, float* __restrict__ dst,
                             const int* __restrict__ flags) {
  int i = blockIdx.x * 256 + threadIdx.x;
  if (i >= tab.total) return;
  int seg = 0;
#pragma unroll
  for (int k = 1; k < NSEG; k++)
    if (i >= tab.off[k]) seg = k;
  int j = i - tab.off[seg];
  const void* src = tab.src[seg];
  dst[i] = flags[0] ? ((const float*)src)[j]
                    : bfbits2f((unsigned int)((const unsigned short*)src)[j]);
}

__device__ __forceinline__ int edge_idx(const int* __restrict__ ei, long pos, int is64) {
  return is64 ? ei[2 * pos] : ei[pos];
}

// ---- fold relation transforms into K/V weights: emit bf16 TRANSPOSED WT[n][k] ----
__global__ void k_eff(const float* __restrict__ Wk, const float* __restrict__ bk,
                      const float* __restrict__ Wv, const float* __restrict__ bv,
                      const float* __restrict__ ar, const float* __restrict__ mr,
                      unsigned short* __restrict__ wkeT, float* __restrict__ bke,
                      unsigned short* __restrict__ wveT, float* __restrict__ bve) {
  int c = blockIdx.x, h = blockIdx.y, z = blockIdx.z;
  int l = z >> 1, which = z & 1;
  int e = threadIdx.x;
  const float* W = (which ? Wv : Wk) + (size_t)l * CD * CD;
  const float* B = (which ? bv : bk) + (size_t)l * CD;
  const float* R = (which ? mr : ar) + (size_t)l * HH * DH * DH + h * DH * DH;
  unsigned short* WoT = (which ? wveT : wkeT) + (size_t)l * CD * CD;
  float* Bo = (which ? bve : bke) + (size_t)l * CD;
  float acc = 0.f;
  if (c < CD) {
#pragma unroll
    for (int d = 0; d < DH; d++) acc += W[c * CD + h * DH + d] * R[d * DH + e];
    WoT[(size_t)(h * DH + e) * CD + c] = f2bfbits(acc);  // transposed [n][k]
  } else {
#pragma unroll
    for (int d = 0; d < DH; d++) acc += B[h * DH + d] * R[d * DH + e];
    Bo[h * DH + e] = acc;
  }
}

// ---- transpose Wq/Wa to bf16 WT[n][k], both layers ----
__global__ void k_wt(const float* __restrict__ Wq, const float* __restrict__ Wa,
                     unsigned short* __restrict__ WqT, unsigned short* __restrict__ WaT) {
  int cout = blockIdx.x, z = blockIdx.y;
  int l = z >> 1, which = z & 1;
  int cin = threadIdx.x;
  const float* W = (which ? Wa : Wq) + (size_t)l * CD * CD;
  unsigned short* WT = (which ? WaT : WqT) + (size_t)l * CD * CD;
  WT[(size_t)cout * CD + cin] = f2bfbits(W[(size_t)cin * CD + cout]);
}

// ==== MFMA GEMM, zero-LDS: y[N,128] = A[N,128](bf16) @ W + b.
// OUT_MODE: 0 = f32; 1 = bf16; 2 = gated residual -> h(f32) + h16(bf16). ====
template <int OUT_MODE>
__global__ __launch_bounds__(256) void k_gemm_mfma(
    const unsigned short* __restrict__ A, const unsigned short* __restrict__ BT,
    const float* __restrict__ bias, void* __restrict__ y,
    float* __restrict__ h, unsigned short* __restrict__ h16,
    const float* __restrict__ skip, int nrows) {
  const int w = threadIdx.x >> 6;
  const int l = threadIdx.x & 63;
  const int r0 = blockIdx.x * 64 + w * 16;
  if (r0 >= nrows) return;
  const int lrow = l & 15;
  const int quad = l >> 4;
  const int k0 = quad * 8;

  f32x4 acc[8];
#pragma unroll
  for (int ct = 0; ct < 8; ct++) {
    float b = bias[ct * 16 + lrow];
    acc[ct] = (f32x4){b, b, b, b};
  }
  int ar = r0 + lrow;
  if (ar >= nrows) ar = nrows - 1;  // clamp; masked on store
  const unsigned short* Ap = A + (size_t)ar * CD;
#pragma unroll
  for (int kc = 0; kc < 4; kc++) {
    bf16x8 af = *(const bf16x8*)(Ap + kc * 32 + k0);
#pragma unroll
    for (int ct = 0; ct < 8; ct++) {
      bf16x8 bfr = *(const bf16x8*)(BT + (size_t)(ct * 16 + lrow) * CD + kc * 32 + k0);
      acc[ct] = __builtin_amdgcn_mfma_f32_16x16x32_bf16(af, bfr, acc[ct], 0, 0, 0);
    }
  }
  float gg = 0.f;
  if (OUT_MODE == 2) gg = 1.f / (1.f + __expf(-skip[0]));
#pragma unroll
  for (int ct = 0; ct < 8; ct++) {
#pragma unroll
    for (int i = 0; i < 4; i++) {
      int gr = r0 + quad * 4 + i;
      if (gr >= nrows) continue;
      int col = ct * 16 + lrow;
      float val = acc[ct][i];
      if (OUT_MODE == 0) {
        ((float*)y)[(size_t)gr * CD + col] = val;
      } else if (OUT_MODE == 1) {
        ((unsigned short*)y)[(size_t)gr * CD + col] = f2bfbits(val);
      } else {
        size_t ix = (size_t)gr * CD + col;
        float o = gg * val + (1.f - gg) * h[ix];
        h[ix] = o;
        h16[ix] = f2bfbits(o);
      }
    }
  }
}

// ==== CSR build (multisplit to kill scatter write-bounce) ====
// per-node degree + coarse-bucket histogram in one pass
__global__ void k_hist2(const int* __restrict__ ei, int* __restrict__ deg,
                        int* __restrict__ bcnt, const int* __restrict__ flags,
                        int E, int Nn, int shift) {
  int i = blockIdx.x * blockDim.x + threadIdx.x;
  if (i >= E) return;
  int d = edge_idx(ei, (long)E + i, flags[1]);
  if ((unsigned)d >= (unsigned)Nn) d = 0;
  atomicAdd(&deg[d], 1);
  atomicAdd(&bcnt[d >> shift], 1);
}

__global__ void k_scan1(const int* __restrict__ deg, int* __restrict__ tmp,
                        int* __restrict__ bsum, int n) {
  __shared__ int sh[256];
  int i = blockIdx.x * 256 + threadIdx.x;
  int v = (i < n) ? deg[i] : 0;
  sh[threadIdx.x] = v;
  __syncthreads();
  for (int off = 1; off < 256; off <<= 1) {
    int t = (threadIdx.x >= off) ? sh[threadIdx.x - off] : 0;
    __syncthreads();
    sh[threadIdx.x] += t;
    __syncthreads();
  }
  if (i < n) tmp[i] = sh[threadIdx.x];
  if (threadIdx.x == 255) bsum[blockIdx.x] = sh[255];
}

__global__ void k_scan2(int* __restrict__ bsum, int nb) {
  __shared__ int sh[256];
  __shared__ int carry;
  if (threadIdx.x == 0) carry = 0;
  __syncthreads();
  for (int base = 0; base < nb; base += 256) {
    int i = base + threadIdx.x;
    int v = (i < nb) ? bsum[i] : 0;
    sh[threadIdx.x] = v;
    __syncthreads();
    for (int off = 1; off < 256; off <<= 1) {
      int t = (threadIdx.x >= off) ? sh[threadIdx.x - off] : 0;
      __syncthreads();
      sh[threadIdx.x] += t;
      __syncthreads();
    }
    if (i < nb) bsum[i] = sh[threadIdx.x] + carry;
    __syncthreads();
    if (threadIdx.x == 0) carry += sh[255];
    __syncthreads();
  }
}

__global__ void k_scan3(const int* __restrict__ tmp, const int* __restrict__ deg,
                        const int* __restrict__ bsum, int* __restrict__ rowptr,
                        int* __restrict__ fill, int n) {
  int i = blockIdx.x * 256 + threadIdx.x;
  if (i >= n) return;
  int off = (blockIdx.x > 0) ? bsum[blockIdx.x - 1] : 0;
  int excl = tmp[i] - deg[i] + off;
  rowptr[i] = excl;
  fill[i] = excl;
}

// exclusive scan of 256 bucket counts -> bbase; also init bfill
__global__ void k_bscan(const int* __restrict__ bcnt, int* __restrict__ bbase,
                        int* __restrict__ bfill) {
  __shared__ int sh[256];
  int t = threadIdx.x;
  int v = bcnt[t];
  sh[t] = v;
  __syncthreads();
  for (int off = 1; off < 256; off <<= 1) {
    int u = (t >= off) ? sh[t - off] : 0;
    __syncthreads();
    sh[t] += u;
    __syncthreads();
  }
  int excl = sh[t] - v;
  bbase[t] = excl;
  bfill[t] = excl;
}

// bin 4096-edge tiles into coarse buckets with clustered global writes
#define BTILE 4096
__global__ __launch_bounds__(256) void k_bin(
    const int* __restrict__ ei, int* __restrict__ bfill,
    int* __restrict__ ebs, int* __restrict__ ebd,
    const int* __restrict__ flags, int E, int Nn, int shift) {
  __shared__ int sS[BTILE];
  __shared__ int sD[BTILE];
  __shared__ int cnt[256], pref[256], base[256], lofs[256];
  const int t = threadIdx.x;
  cnt[t] = 0;
  lofs[t] = 0;
  __syncthreads();
  const int t0 = blockIdx.x * BTILE;
  const int is64 = flags[1];
  // A: count buckets
  for (int j = 0; j < 16; j++) {
    int i = t0 + t + j * 256;
    if (i < E) {
      int d = edge_idx(ei, (long)E + i, is64);
      if ((unsigned)d >= (unsigned)Nn) d = 0;
      atomicAdd(&cnt[d >> shift], 1);
    }
  }
  __syncthreads();
  // B: block-exclusive prefix; D: reserve global runs
  {
    int v = cnt[t];
    pref[t] = v;
    __syncthreads();
    for (int off = 1; off < 256; off <<= 1) {
      int u = (t >= off) ? pref[t - off] : 0;
      __syncthreads();
      pref[t] += u;
      __syncthreads();
    }
    int incl = pref[t];
    __syncthreads();
    pref[t] = incl - v;
    base[t] = (v > 0) ? atomicAdd(&bfill[t], v) : 0;
  }
  __syncthreads();
  // C: reorder (src,dst) into LDS by bucket
  for (int j = 0; j < 16; j++) {
    int i = t0 + t + j * 256;
    if (i < E) {
      int s = edge_idx(ei, (long)i, is64);
      int d = edge_idx(ei, (long)E + i, is64);
      if ((unsigned)s >= (unsigned)Nn) s = 0;
      if ((unsigned)d >= (unsigned)Nn) d = 0;
      int b = d >> shift;
      int p = pref[b] + atomicAdd(&lofs[b], 1);
      sS[p] = s;
      sD[p] = d;
    }
  }
  __syncthreads();
  // E: clustered write-out (runs per bucket are contiguous)
  int tot = E - t0;
  if (tot > BTILE) tot = BTILE;
  for (int j = 0; j < 16; j++) {
    int i = t + j * 256;
    if (i < tot) {
      int d = sD[i];
      int b = d >> shift;
      int gp = base[b] + (i - pref[b]);
      ebs[gp] = sS[i];
      ebd[gp] = d;
    }
  }
}

// final scatter within per-bucket csr window (L2-local)
__global__ void k_scatter2(const int* __restrict__ bbase, const int* __restrict__ bcnt,
                           const int* __restrict__ ebs, const int* __restrict__ ebd,
                           int* __restrict__ fill, int* __restrict__ csr_src) {
  int b = blockIdx.x >> 1, half = blockIdx.x & 1;
  int s0 = bbase[b], c = bcnt[b];
  int st = s0 + (half ? (c + 1) / 2 : 0);
  int en = s0 + (half ? c : (c + 1) / 2);
  for (int i = st + threadIdx.x; i < en; i += 256) {
    int s = ebs[i], d = ebd[i];
    int pos = atomicAdd(&fill[d], 1);
    csr_src[pos] = s;
  }
}

// ==== fused attention, k/v bf16; epilogue applies GELU and packs bf16 agg16. ====
__global__ __launch_bounds__(256) void k_edge(
    const float* __restrict__ q, const unsigned short* __restrict__ kk,
    const unsigned short* __restrict__ v, const int* __restrict__ rowptr,
    const int* __restrict__ deg, const int* __restrict__ csr_src,
    const float* __restrict__ p_rel, unsigned short* __restrict__ agg16, int N) {
  int n = (blockIdx.x * 256 + threadIdx.x) >> 6;
  if (n >= N) return;
  const int lane = threadIdx.x & 63;
  const int g = lane >> 4;
  const int j = lane & 15;
  const int start = rowptr[n];
  const int end = start + deg[n];
  const float prl = p_rel[j >> 2] * 0.17677669529663687f;  // 1/sqrt(32)
  const float4 qa = *(const float4*)(q + (size_t)n * CD + 8 * j);
  const float4 qb = *(const float4*)(q + (size_t)n * CD + 8 * j + 4);
  float m = -INFINITY, den = 0.f;
  float acc[8] = {0.f, 0.f, 0.f, 0.f, 0.f, 0.f, 0.f, 0.f};
  for (int e = start + g; e < end; e += 4) {
    int s = csr_src[e];
    uint4 ku = *(const uint4*)(kk + (size_t)s * CD + 8 * j);  // 8 bf16 = 16 B
    uint4 vu = *(const uint4*)(v + (size_t)s * CD + 8 * j);
    float k0 = bfbits2f(ku.x & 0xffffu), k1 = bfbits2f(ku.x >> 16);
    float k2 = bfbits2f(ku.y & 0xffffu), k3 = bfbits2f(ku.y >> 16);
    float k4 = bfbits2f(ku.z & 0xffffu), k5 = bfbits2f(ku.z >> 16);
    float k6 = bfbits2f(ku.w & 0xffffu), k7 = bfbits2f(ku.w >> 16);
    float v0 = bfbits2f(vu.x & 0xffffu), v1 = bfbits2f(vu.x >> 16);
    float v2 = bfbits2f(vu.y & 0xffffu), v3 = bfbits2f(vu.y >> 16);
    float v4 = bfbits2f(vu.z & 0xffffu), v5 = bfbits2f(vu.z >> 16);
    float v6 = bfbits2f(vu.w & 0xffffu), v7 = bfbits2f(vu.w >> 16);
    float pd = qa.x * k0 + qa.y * k1 + qa.z * k2 + qa.w * k3 +
               qb.x * k4 + qb.y * k5 + qb.z * k6 + qb.w * k7;
    pd += __shfl_xor(pd, 1);
    pd += __shfl_xor(pd, 2);
    float a = pd * prl;
    float mn = fmaxf(m, a);
    float sc = __expf(m - mn);
    float ew = __expf(a - mn);
    acc[0] = acc[0] * sc + ew * v0; acc[1] = acc[1] * sc + ew * v1;
    acc[2] = acc[2] * sc + ew * v2; acc[3] = acc[3] * sc + ew * v3;
    acc[4] = acc[4] * sc + ew * v4; acc[5] = acc[5] * sc + ew * v5;
    acc[6] = acc[6] * sc + ew * v6; acc[7] = acc[7] * sc + ew * v7;
    den = den * sc + ew;
    m = mn;
  }
#pragma unroll
  for (int off = 16; off <= 32; off <<= 1) {
    float mo = __shfl_xor(m, off);
    float dno = __shfl_xor(den, off);
    float ao[8];
#pragma unroll
    for (int i = 0; i < 8; i++) ao[i] = __shfl_xor(acc[i], off);
    float mn = fmaxf(m, mo);
    float s1 = (den > 0.f) ? __expf(m - mn) : 0.f;
    float s2 = (dno > 0.f) ? __expf(mo - mn) : 0.f;
#pragma unroll
    for (int i = 0; i < 8; i++) acc[i] = acc[i] * s1 + ao[i] * s2;
    den = den * s1 + dno * s2;
    m = mn;
  }
  if (g == 0) {
    float inv = (den > 0.f) ? 1.f / den : 0.f;
    ushort4 o0, o1;
    o0.x = f2bfbits(gelu_f(acc[0] * inv)); o0.y = f2bfbits(gelu_f(acc[1] * inv));
    o0.z = f2bfbits(gelu_f(acc[2] * inv)); o0.w = f2bfbits(gelu_f(acc[3] * inv));
    o1.x = f2bfbits(gelu_f(acc[4] * inv)); o1.y = f2bfbits(gelu_f(acc[5] * inv));
    o1.z = f2bfbits(gelu_f(acc[6] * inv)); o1.w = f2bfbits(gelu_f(acc[7] * inv));
    *(ushort4*)(agg16 + (size_t)n * CD + 8 * j) = o0;
    *(ushort4*)(agg16 + (size_t)n * CD + 8 * j + 4) = o1;
  }
}

// ---- out[n,0:2] = h[n,:] @ Wfc + bfc; f32 out if flags[0] else bf16 ----
__global__ __launch_bounds__(256) void k_final(const float* __restrict__ h,
                                               const float* __restrict__ Wfc,
                                               const float* __restrict__ bfc,
                                               void* __restrict__ out,
                                               const int* __restrict__ flags, int N) {
  int g = (blockIdx.x * 256 + threadIdx.x) >> 5;
  int lane = threadIdx.x & 31;
  if (g >= N) return;
  const float* hr = h + (size_t)g * CD;
  float a0 = 0.f, a1 = 0.f;
#pragma unroll
  for (int j = 0; j < 4; j++) {
    float hv = hr[lane + 32 * j];
    a0 += hv * Wfc[(lane + 32 * j) * 2];
    a1 += hv * Wfc[(lane + 32 * j) * 2 + 1];
  }
#pragma unroll
  for (int off = 16; off; off >>= 1) {
    a0 += __shfl_xor(a0, off);
    a1 += __shfl_xor(a1, off);
  }
  if (lane == 0) {
    float o0 = a0 + bfc[0];
    float o1 = a1 + bfc[1];
    if (flags[0]) {
      ((float*)out)[(size_t)g * 2] = o0;
      ((float*)out)[(size_t)g * 2 + 1] = o1;
    } else {
      ((bf16*)out)[(size_t)g * 2] = __float2bfloat16(o0);
      ((bf16*)out)[(size_t)g * 2 + 1] = __float2bfloat16(o1);
    }
  }
}

extern "C" void kernel_launch(void* const* d_in, const int* in_sizes, int n_in,
                              void* d_out, int out_size, void* d_ws, size_t ws_size,
                              hipStream_t stream) {
  const int* ei = (const int*)d_in[1];
  const int N = in_sizes[0] / CD;
  const int E = in_sizes[1] / 2;
  const size_t NC = (size_t)N * CD;
  const int nB = (N + 255) / 256;
  int shift = 0;
  while (((N - 1) >> shift) >= 256) shift++;  // 256 coarse buckets

  float* p = (float*)d_ws;
  float* hbuf = p;                                    // NC f32
  float* qbuf = p + NC;                               // NC f32
  float* cur = p + 2 * NC;
  unsigned short* hbuf16 = (unsigned short*)cur; cur += NC / 2;
  unsigned short* kbuf16 = (unsigned short*)cur; cur += NC / 2;
  unsigned short* vbuf16 = (unsigned short*)cur; cur += NC / 2;
  unsigned short* agg16 = (unsigned short*)cur; cur += NC / 2;
  int* ip = (int*)cur;
  int* deg = ip;
  int* tmp = ip + N;
  int* rowptr = ip + 2 * N;
  int* fill = ip + 3 * N;
  int* bsum = ip + 4 * N;
  int* csr_src = ip + 4 * N + nB;
  int* bcnt = csr_src + E;     // 256
  int* bbase = bcnt + 256;     // 256
  int* bfill = bbase + 256;    // 256
  cur = (float*)(bfill + 256);
  unsigned short* wkeT = (unsigned short*)cur; cur += (size_t)LL * CD * CD / 2;
  unsigned short* wveT = (unsigned short*)cur; cur += (size_t)LL * CD * CD / 2;
  unsigned short* wqT = (unsigned short*)cur; cur += (size_t)LL * CD * CD / 2;
  unsigned short* waT = (unsigned short*)cur; cur += (size_t)LL * CD * CD / 2;
  float* bke = cur; cur += (size_t)LL * CD;
  float* bve = cur; cur += (size_t)LL * CD;
  float* pblock = cur;
  float* pWk = cur; cur += (size_t)LL * CD * CD;
  float* pbk = cur; cur += (size_t)LL * CD;
  float* pWq = cur; cur += (size_t)LL * CD * CD;
  float* pbq = cur; cur += (size_t)LL * CD;
  float* pWv = cur; cur += (size_t)LL * CD * CD;
  float* pbv = cur; cur += (size_t)LL * CD;
  float* par = cur; cur += (size_t)LL * HH * DH * DH;
  float* pmr = cur; cur += (size_t)LL * HH * DH * DH;
  float* ppr = cur; cur += (size_t)LL * HH;
  float* pWa = cur; cur += (size_t)LL * CD * CD;
  float* pba = cur; cur += (size_t)LL * CD;
  float* pskip = cur; cur += LL;
  float* pWfc = cur; cur += (size_t)CD * 2;
  float* pbfc = cur; cur += 2;
  int* flags = (int*)cur;

  // binned-edge staging aliases kbuf16/vbuf16 (only used before layer loop)
  int* ebs = (int*)kbuf16;       // E ints
  int* ebd = ebs + E;            // E ints (fits: kbuf16+vbuf16 = 2*NC bytes)

  k_detect<<<1, 128, 0, stream>>>(d_in[0], ei, flags);
  k_cvt_x<<<((int)NC + 255) / 256, 256, 0, stream>>>(d_in[0], hbuf, hbuf16,
                                                     (int)NC, flags);

  SegTab tab;
  const int sizes[NSEG] = {LL * CD * CD, LL * CD, LL * CD * CD, LL * CD,
                           LL * CD * CD, LL * CD, LL * HH * DH * DH,
                           LL * HH * DH * DH, LL * HH, LL * CD * CD, LL * CD,
                           LL, CD * 2, 2};
  const int srcIdx[NSEG] = {2, 3, 4, 5, 6, 7, 8, 9, 10, 11, 12, 13, 14, 15};
  int off = 0;
  for (int k = 0; k < NSEG; k++) {
    tab.src[k] = d_in[srcIdx[k]];
    tab.off[k] = off;
    off += sizes[k];
  }
  tab.total = off;
  k_cvt_params<<<(off + 255) / 256, 256, 0, stream>>>(tab, pblock, flags);

  k_eff<<<dim3(CD + 1, HH, LL * 2), DH, 0, stream>>>(pWk, pbk, pWv, pbv, par, pmr,
                                                     wkeT, bke, wveT, bve);
  k_wt<<<dim3(CD, 2 * LL), CD, 0, stream>>>(pWq, pWa, wqT, waT);

  // ---- CSR build with multisplit ----
  hipMemsetAsync(deg, 0, (size_t)N * sizeof(int), stream);
  hipMemsetAsync(bcnt, 0, 256 * sizeof(int), stream);
  k_hist2<<<(E + 255) / 256, 256, 0, stream>>>(ei, deg, bcnt, flags, E, N, shift);
  k_scan1<<<nB, 256, 0, stream>>>(deg, tmp, bsum, N);
  k_scan2<<<1, 256, 0, stream>>>(bsum, nB);
  k_scan3<<<nB, 256, 0, stream>>>(tmp, deg, bsum, rowptr, fill, N);
  k_bscan<<<1, 256, 0, stream>>>(bcnt, bbase, bfill);
  k_bin<<<(E + BTILE - 1) / BTILE, 256, 0, stream>>>(ei, bfill, ebs, ebd, flags,
                                                     E, N, shift);
  k_scatter2<<<512, 256, 0, stream>>>(bbase, bcnt, ebs, ebd, fill, csr_src);

  const int mfmaBlocks = (N + 63) / 64;
  for (int l = 0; l < LL; l++) {
    k_gemm_mfma<0><<<mfmaBlocks, 256, 0, stream>>>(
        hbuf16, wqT + (size_t)l * CD * CD, pbq + (size_t)l * CD, qbuf,
        nullptr, nullptr, nullptr, N);
    k_gemm_mfma<1><<<mfmaBlocks, 256, 0, stream>>>(
        hbuf16, wkeT + (size_t)l * CD * CD, bke + (size_t)l * CD, kbuf16,
        nullptr, nullptr, nullptr, N);
    k_gemm_mfma<1><<<mfmaBlocks, 256, 0, stream>>>(
        hbuf16, wveT + (size_t)l * CD * CD, bve + (size_t)l * CD, vbuf16,
        nullptr, nullptr, nullptr, N);

    k_edge<<<(N + 3) / 4, 256, 0, stream>>>(qbuf, kbuf16, vbuf16, rowptr, deg,
                                            csr_src, ppr + (size_t)l * HH, agg16, N);

    // gelu(agg)@Wa + ba, gated residual -> hbuf (f32) + hbuf16 (bf16)
    k_gemm_mfma<2><<<mfmaBlocks, 256, 0, stream>>>(
        agg16, waT + (size_t)l * CD * CD, pba + (size_t)l * CD, nullptr,
        hbuf, hbuf16, pskip + l, N);
  }
  k_final<<<(N + 7) / 8, 256, 0, stream>>>(hbuf, pWfc, pbfc, d_out, flags, N);
}

// Round 13
// 872.770 us; speedup vs baseline: 2.0033x; 2.0033x over previous
//
#include <hip/hip_runtime.h>
#include <hip/hip_bf16.h>
#include <math.h>

#define CD 128
#define HH 4
#define DH 32
#define LL 2

using bf16 = __hip_bfloat16;
using bf16x8 = __attribute__((ext_vector_type(8))) short;  // 8 bf16 (4 VGPRs)
using f32x4 = __attribute__((ext_vector_type(4))) float;

__device__ __forceinline__ float bfbits2f(unsigned int s) {
  return __uint_as_float(s << 16);
}

__device__ __forceinline__ unsigned short f2bfbits(float f) {
  unsigned int u = __float_as_uint(f);
  unsigned int r = (u + 0x7fff + ((u >> 16) & 1)) >> 16;  // RNE
  return (unsigned short)r;
}

__device__ __forceinline__ float gelu_f(float x) {
  return 0.5f * x * (1.0f + erff(x * 0.70710678118654752f));
}

// ---- detect input formats: flags[0]=floats-are-f32, flags[1]=edge-index-is-i64 ----
__global__ void k_detect(const void* __restrict__ x, const int* __restrict__ ei,
                         int* __restrict__ flags) {
  __shared__ int cnt_f32, cnt_i32;
  if (threadIdx.x == 0) { cnt_f32 = 0; cnt_i32 = 0; }
  __syncthreads();
  int t = threadIdx.x;  // 128 threads
  unsigned short u = ((const unsigned short*)x)[2 * t];
  float v = bfbits2f((unsigned int)u);
  float av = fabsf(v);
  if (av != 0.f && (av > 1e8f || av < 1e-8f)) atomicAdd(&cnt_f32, 1);
  if (t < 64) {
    if (((const int*)ei)[2 * t + 1] != 0) atomicAdd(&cnt_i32, 1);
  }
  __syncthreads();
  if (threadIdx.x == 0) {
    flags[0] = (cnt_f32 > 8) ? 1 : 0;
    flags[1] = (cnt_i32 == 0) ? 1 : 0;
  }
}

// ---- x -> f32 hbuf AND bf16 hbuf16 ----
__global__ void k_cvt_x(const void* __restrict__ in, float* __restrict__ out,
                        unsigned short* __restrict__ out16, int n,
                        const int* __restrict__ flags) {
  int i = blockIdx.x * blockDim.x + threadIdx.x;
  if (i >= n) return;
  float v = flags[0] ? ((const float*)in)[i]
                     : bfbits2f((unsigned int)((const unsigned short*)in)[i]);
  out[i] = v;
  out16[i] = f2bfbits(v);
}

// ---- all parameter tensors -> contiguous f32 block, one launch ----
#define NSEG 14
struct SegTab {
  const void* src[NSEG];
  int off[NSEG];
  int total;
};
__global__ void k_cvt_params(SegTab tab, float* __restrict__ dst,
                             const int* __restrict__ flags) {
  int i = blockIdx.x * 256 + threadIdx.x;
  if (i >= tab.total) return;
  int seg = 0;
#pragma unroll
  for (int k = 1; k < NSEG; k++)
    if (i >= tab.off[k]) seg = k;
  int j = i - tab.off[seg];
  const void* src = tab.src[seg];
  dst[i] = flags[0] ? ((const float*)src)[j]
                    : bfbits2f((unsigned int)((const unsigned short*)src)[j]);
}

__device__ __forceinline__ int edge_idx(const int* __restrict__ ei, long pos, int is64) {
  return is64 ? ei[2 * pos] : ei[pos];
}

// ---- fold relation transforms into K/V weights: emit bf16 TRANSPOSED WT[n][k] ----
__global__ void k_eff(const float* __restrict__ Wk, const float* __restrict__ bk,
                      const float* __restrict__ Wv, const float* __restrict__ bv,
                      const float* __restrict__ ar, const float* __restrict__ mr,
                      unsigned short* __restrict__ wkeT, float* __restrict__ bke,
                      unsigned short* __restrict__ wveT, float* __restrict__ bve) {
  int c = blockIdx.x, h = blockIdx.y, z = blockIdx.z;
  int l = z >> 1, which = z & 1;
  int e = threadIdx.x;
  const float* W = (which ? Wv : Wk) + (size_t)l * CD * CD;
  const float* B = (which ? bv : bk) + (size_t)l * CD;
  const float* R = (which ? mr : ar) + (size_t)l * HH * DH * DH + h * DH * DH;
  unsigned short* WoT = (which ? wveT : wkeT) + (size_t)l * CD * CD;
  float* Bo = (which ? bve : bke) + (size_t)l * CD;
  float acc = 0.f;
  if (c < CD) {
#pragma unroll
    for (int d = 0; d < DH; d++) acc += W[c * CD + h * DH + d] * R[d * DH + e];
    WoT[(size_t)(h * DH + e) * CD + c] = f2bfbits(acc);  // transposed [n][k]
  } else {
#pragma unroll
    for (int d = 0; d < DH; d++) acc += B[h * DH + d] * R[d * DH + e];
    Bo[h * DH + e] = acc;
  }
}

// ---- transpose Wq/Wa to bf16 WT[n][k], both layers ----
__global__ void k_wt(const float* __restrict__ Wq, const float* __restrict__ Wa,
                     unsigned short* __restrict__ WqT, unsigned short* __restrict__ WaT) {
  int cout = blockIdx.x, z = blockIdx.y;
  int l = z >> 1, which = z & 1;
  int cin = threadIdx.x;
  const float* W = (which ? Wa : Wq) + (size_t)l * CD * CD;
  unsigned short* WT = (which ? WaT : WqT) + (size_t)l * CD * CD;
  WT[(size_t)cout * CD + cin] = f2bfbits(W[(size_t)cin * CD + cout]);
}

// ==== MFMA GEMM, zero-LDS: y[N,128] = A[N,128](bf16) @ W + b.
// OUT_MODE: 0 = f32; 1 = bf16; 2 = gated residual -> h(f32) + h16(bf16). ====
template <int OUT_MODE>
__global__ __launch_bounds__(256) void k_gemm_mfma(
    const unsigned short* __restrict__ A, const unsigned short* __restrict__ BT,
    const float* __restrict__ bias, void* __restrict__ y,
    float* __restrict__ h, unsigned short* __restrict__ h16,
    const float* __restrict__ skip, int nrows) {
  const int w = threadIdx.x >> 6;
  const int l = threadIdx.x & 63;
  const int r0 = blockIdx.x * 64 + w * 16;
  if (r0 >= nrows) return;
  const int lrow = l & 15;
  const int quad = l >> 4;
  const int k0 = quad * 8;

  f32x4 acc[8];
#pragma unroll
  for (int ct = 0; ct < 8; ct++) {
    float b = bias[ct * 16 + lrow];
    acc[ct] = (f32x4){b, b, b, b};
  }
  int ar = r0 + lrow;
  if (ar >= nrows) ar = nrows - 1;  // clamp; masked on store
  const unsigned short* Ap = A + (size_t)ar * CD;
#pragma unroll
  for (int kc = 0; kc < 4; kc++) {
    bf16x8 af = *(const bf16x8*)(Ap + kc * 32 + k0);
#pragma unroll
    for (int ct = 0; ct < 8; ct++) {
      bf16x8 bfr = *(const bf16x8*)(BT + (size_t)(ct * 16 + lrow) * CD + kc * 32 + k0);
      acc[ct] = __builtin_amdgcn_mfma_f32_16x16x32_bf16(af, bfr, acc[ct], 0, 0, 0);
    }
  }
  float gg = 0.f;
  if (OUT_MODE == 2) gg = 1.f / (1.f + __expf(-skip[0]));
#pragma unroll
  for (int ct = 0; ct < 8; ct++) {
#pragma unroll
    for (int i = 0; i < 4; i++) {
      int gr = r0 + quad * 4 + i;
      if (gr >= nrows) continue;
      int col = ct * 16 + lrow;
      float val = acc[ct][i];
      if (OUT_MODE == 0) {
        ((float*)y)[(size_t)gr * CD + col] = val;
      } else if (OUT_MODE == 1) {
        ((unsigned short*)y)[(size_t)gr * CD + col] = f2bfbits(val);
      } else {
        size_t ix = (size_t)gr * CD + col;
        float o = gg * val + (1.f - gg) * h[ix];
        h[ix] = o;
        h16[ix] = f2bfbits(o);
      }
    }
  }
}

// ==== CSR build (multisplit; bucket hist LDS-aggregated to avoid hot atomics) ====
__global__ void k_hist(const int* __restrict__ ei, int* __restrict__ deg,
                       const int* __restrict__ flags, int E, int Nn) {
  int i = blockIdx.x * blockDim.x + threadIdx.x;
  if (i >= E) return;
  int d = edge_idx(ei, (long)E + i, flags[1]);
  if ((unsigned)d >= (unsigned)Nn) d = 0;
  atomicAdd(&deg[d], 1);
}

#define BTILE 4096
// per-tile LDS histogram of 256 coarse buckets -> one global atomic per bucket
__global__ __launch_bounds__(256) void k_bcount(
    const int* __restrict__ ei, int* __restrict__ bcnt,
    const int* __restrict__ flags, int E, int Nn, int shift) {
  __shared__ int cnt[256];
  cnt[threadIdx.x] = 0;
  __syncthreads();
  const int t0 = blockIdx.x * BTILE;
  const int is64 = flags[1];
  for (int j = 0; j < 16; j++) {
    int i = t0 + threadIdx.x + j * 256;
    if (i < E) {
      int d = edge_idx(ei, (long)E + i, is64);
      if ((unsigned)d >= (unsigned)Nn) d = 0;
      atomicAdd(&cnt[d >> shift], 1);
    }
  }
  __syncthreads();
  int v = cnt[threadIdx.x];
  if (v > 0) atomicAdd(&bcnt[threadIdx.x], v);
}

__global__ void k_scan1(const int* __restrict__ deg, int* __restrict__ tmp,
                        int* __restrict__ bsum, int n) {
  __shared__ int sh[256];
  int i = blockIdx.x * 256 + threadIdx.x;
  int v = (i < n) ? deg[i] : 0;
  sh[threadIdx.x] = v;
  __syncthreads();
  for (int off = 1; off < 256; off <<= 1) {
    int t = (threadIdx.x >= off) ? sh[threadIdx.x - off] : 0;
    __syncthreads();
    sh[threadIdx.x] += t;
    __syncthreads();
  }
  if (i < n) tmp[i] = sh[threadIdx.x];
  if (threadIdx.x == 255) bsum[blockIdx.x] = sh[255];
}

__global__ void k_scan2(int* __restrict__ bsum, int nb) {
  __shared__ int sh[256];
  __shared__ int carry;
  if (threadIdx.x == 0) carry = 0;
  __syncthreads();
  for (int base = 0; base < nb; base += 256) {
    int i = base + threadIdx.x;
    int v = (i < nb) ? bsum[i] : 0;
    sh[threadIdx.x] = v;
    __syncthreads();
    for (int off = 1; off < 256; off <<= 1) {
      int t = (threadIdx.x >= off) ? sh[threadIdx.x - off] : 0;
      __syncthreads();
      sh[threadIdx.x] += t;
      __syncthreads();
    }
    if (i < nb) bsum[i] = sh[threadIdx.x] + carry;
    __syncthreads();
    if (threadIdx.x == 0) carry += sh[255];
    __syncthreads();
  }
}

__global__ void k_scan3(const int* __restrict__ tmp, const int* __restrict__ deg,
                        const int* __restrict__ bsum, int* __restrict__ rowptr,
                        int* __restrict__ fill, int n) {
  int i = blockIdx.x * 256 + threadIdx.x;
  if (i >= n) return;
  int off = (blockIdx.x > 0) ? bsum[blockIdx.x - 1] : 0;
  int excl = tmp[i] - deg[i] + off;
  rowptr[i] = excl;
  fill[i] = excl;
}

// exclusive scan of 256 bucket counts -> bbase; also init bfill
__global__ void k_bscan(const int* __restrict__ bcnt, int* __restrict__ bbase,
                        int* __restrict__ bfill) {
  __shared__ int sh[256];
  int t = threadIdx.x;
  int v = bcnt[t];
  sh[t] = v;
  __syncthreads();
  for (int off = 1; off < 256; off <<= 1) {
    int u = (t >= off) ? sh[t - off] : 0;
    __syncthreads();
    sh[t] += u;
    __syncthreads();
  }
  int excl = sh[t] - v;
  bbase[t] = excl;
  bfill[t] = excl;
}

// bin 4096-edge tiles into coarse buckets with clustered global writes
__global__ __launch_bounds__(256) void k_bin(
    const int* __restrict__ ei, int* __restrict__ bfill,
    int* __restrict__ ebs, int* __restrict__ ebd,
    const int* __restrict__ flags, int E, int Nn, int shift) {
  __shared__ int sS[BTILE];
  __shared__ int sD[BTILE];
  __shared__ int cnt[256], pref[256], base[256], lofs[256];
  const int t = threadIdx.x;
  cnt[t] = 0;
  lofs[t] = 0;
  __syncthreads();
  const int t0 = blockIdx.x * BTILE;
  const int is64 = flags[1];
  // A: count buckets
  for (int j = 0; j < 16; j++) {
    int i = t0 + t + j * 256;
    if (i < E) {
      int d = edge_idx(ei, (long)E + i, is64);
      if ((unsigned)d >= (unsigned)Nn) d = 0;
      atomicAdd(&cnt[d >> shift], 1);
    }
  }
  __syncthreads();
  // B: block-exclusive prefix; reserve global runs
  {
    int v = cnt[t];
    pref[t] = v;
    __syncthreads();
    for (int off = 1; off < 256; off <<= 1) {
      int u = (t >= off) ? pref[t - off] : 0;
      __syncthreads();
      pref[t] += u;
      __syncthreads();
    }
    int incl = pref[t];
    __syncthreads();
    pref[t] = incl - v;
    base[t] = (v > 0) ? atomicAdd(&bfill[t], v) : 0;
  }
  __syncthreads();
  // C: reorder (src,dst) into LDS by bucket
  for (int j = 0; j < 16; j++) {
    int i = t0 + t + j * 256;
    if (i < E) {
      int s = edge_idx(ei, (long)i, is64);
      int d = edge_idx(ei, (long)E + i, is64);
      if ((unsigned)s >= (unsigned)Nn) s = 0;
      if ((unsigned)d >= (unsigned)Nn) d = 0;
      int b = d >> shift;
      int p = pref[b] + atomicAdd(&lofs[b], 1);
      sS[p] = s;
      sD[p] = d;
    }
  }
  __syncthreads();
  // E: clustered write-out (runs per bucket are contiguous)
  int tot = E - t0;
  if (tot > BTILE) tot = BTILE;
  for (int j = 0; j < 16; j++) {
    int i = t + j * 256;
    if (i < tot) {
      int d = sD[i];
      int b = d >> shift;
      int gp = base[b] + (i - pref[b]);
      ebs[gp] = sS[i];
      ebd[gp] = d;
    }
  }
}

// final scatter within per-bucket csr window (L2-local)
__global__ void k_scatter2(const int* __restrict__ bbase, const int* __restrict__ bcnt,
                           const int* __restrict__ ebs, const int* __restrict__ ebd,
                           int* __restrict__ fill, int* __restrict__ csr_src) {
  int b = blockIdx.x >> 1, half = blockIdx.x & 1;
  int s0 = bbase[b], c = bcnt[b];
  int st = s0 + (half ? (c + 1) / 2 : 0);
  int en = s0 + (half ? c : (c + 1) / 2);
  for (int i = st + threadIdx.x; i < en; i += 256) {
    int s = ebs[i], d = ebd[i];
    int pos = atomicAdd(&fill[d], 1);
    csr_src[pos] = s;
  }
}

// ==== fused attention, k/v bf16; epilogue applies GELU and packs bf16 agg16. ====
__global__ __launch_bounds__(256) void k_edge(
    const float* __restrict__ q, const unsigned short* __restrict__ kk,
    const unsigned short* __restrict__ v, const int* __restrict__ rowptr,
    const int* __restrict__ deg, const int* __restrict__ csr_src,
    const float* __restrict__ p_rel, unsigned short* __restrict__ agg16, int N) {
  int n = (blockIdx.x * 256 + threadIdx.x) >> 6;
  if (n >= N) return;
  const int lane = threadIdx.x & 63;
  const int g = lane >> 4;
  const int j = lane & 15;
  const int start = rowptr[n];
  const int end = start + deg[n];
  const float prl = p_rel[j >> 2] * 0.17677669529663687f;  // 1/sqrt(32)
  const float4 qa = *(const float4*)(q + (size_t)n * CD + 8 * j);
  const float4 qb = *(const float4*)(q + (size_t)n * CD + 8 * j + 4);
  float m = -INFINITY, den = 0.f;
  float acc[8] = {0.f, 0.f, 0.f, 0.f, 0.f, 0.f, 0.f, 0.f};
  for (int e = start + g; e < end; e += 4) {
    int s = csr_src[e];
    uint4 ku = *(const uint4*)(kk + (size_t)s * CD + 8 * j);  // 8 bf16 = 16 B
    uint4 vu = *(const uint4*)(v + (size_t)s * CD + 8 * j);
    float k0 = bfbits2f(ku.x & 0xffffu), k1 = bfbits2f(ku.x >> 16);
    float k2 = bfbits2f(ku.y & 0xffffu), k3 = bfbits2f(ku.y >> 16);
    float k4 = bfbits2f(ku.z & 0xffffu), k5 = bfbits2f(ku.z >> 16);
    float k6 = bfbits2f(ku.w & 0xffffu), k7 = bfbits2f(ku.w >> 16);
    float v0 = bfbits2f(vu.x & 0xffffu), v1 = bfbits2f(vu.x >> 16);
    float v2 = bfbits2f(vu.y & 0xffffu), v3 = bfbits2f(vu.y >> 16);
    float v4 = bfbits2f(vu.z & 0xffffu), v5 = bfbits2f(vu.z >> 16);
    float v6 = bfbits2f(vu.w & 0xffffu), v7 = bfbits2f(vu.w >> 16);
    float pd = qa.x * k0 + qa.y * k1 + qa.z * k2 + qa.w * k3 +
               qb.x * k4 + qb.y * k5 + qb.z * k6 + qb.w * k7;
    pd += __shfl_xor(pd, 1);
    pd += __shfl_xor(pd, 2);
    float a = pd * prl;
    float mn = fmaxf(m, a);
    float sc = __expf(m - mn);
    float ew = __expf(a - mn);
    acc[0] = acc[0] * sc + ew * v0; acc[1] = acc[1] * sc + ew * v1;
    acc[2] = acc[2] * sc + ew * v2; acc[3] = acc[3] * sc + ew * v3;
    acc[4] = acc[4] * sc + ew * v4; acc[5] = acc[5] * sc + ew * v5;
    acc[6] = acc[6] * sc + ew * v6; acc[7] = acc[7] * sc + ew * v7;
    den = den * sc + ew;
    m = mn;
  }
#pragma unroll
  for (int off = 16; off <= 32; off <<= 1) {
    float mo = __shfl_xor(m, off);
    float dno = __shfl_xor(den, off);
    float ao[8];
#pragma unroll
    for (int i = 0; i < 8; i++) ao[i] = __shfl_xor(acc[i], off);
    float mn = fmaxf(m, mo);
    float s1 = (den > 0.f) ? __expf(m - mn) : 0.f;
    float s2 = (dno > 0.f) ? __expf(mo - mn) : 0.f;
#pragma unroll
    for (int i = 0; i < 8; i++) acc[i] = acc[i] * s1 + ao[i] * s2;
    den = den * s1 + dno * s2;
    m = mn;
  }
  if (g == 0) {
    float inv = (den > 0.f) ? 1.f / den : 0.f;
    ushort4 o0, o1;
    o0.x = f2bfbits(gelu_f(acc[0] * inv)); o0.y = f2bfbits(gelu_f(acc[1] * inv));
    o0.z = f2bfbits(gelu_f(acc[2] * inv)); o0.w = f2bfbits(gelu_f(acc[3] * inv));
    o1.x = f2bfbits(gelu_f(acc[4] * inv)); o1.y = f2bfbits(gelu_f(acc[5] * inv));
    o1.z = f2bfbits(gelu_f(acc[6] * inv)); o1.w = f2bfbits(gelu_f(acc[7] * inv));
    *(ushort4*)(agg16 + (size_t)n * CD + 8 * j) = o0;
    *(ushort4*)(agg16 + (size_t)n * CD + 8 * j + 4) = o1;
  }
}

// ---- out[n,0:2] = h[n,:] @ Wfc + bfc; f32 out if flags[0] else bf16 ----
__global__ __launch_bounds__(256) void k_final(const float* __restrict__ h,
                                               const float* __restrict__ Wfc,
                                               const float* __restrict__ bfc,
                                               void* __restrict__ out,
                                               const int* __restrict__ flags, int N) {
  int g = (blockIdx.x * 256 + threadIdx.x) >> 5;
  int lane = threadIdx.x & 31;
  if (g >= N) return;
  const float* hr = h + (size_t)g * CD;
  float a0 = 0.f, a1 = 0.f;
#pragma unroll
  for (int j = 0; j < 4; j++) {
    float hv = hr[lane + 32 * j];
    a0 += hv * Wfc[(lane + 32 * j) * 2];
    a1 += hv * Wfc[(lane + 32 * j) * 2 + 1];
  }
#pragma unroll
  for (int off = 16; off; off >>= 1) {
    a0 += __shfl_xor(a0, off);
    a1 += __shfl_xor(a1, off);
  }
  if (lane == 0) {
    float o0 = a0 + bfc[0];
    float o1 = a1 + bfc[1];
    if (flags[0]) {
      ((float*)out)[(size_t)g * 2] = o0;
      ((float*)out)[(size_t)g * 2 + 1] = o1;
    } else {
      ((bf16*)out)[(size_t)g * 2] = __float2bfloat16(o0);
      ((bf16*)out)[(size_t)g * 2 + 1] = __float2bfloat16(o1);
    }
  }
}

extern "C" void kernel_launch(void* const* d_in, const int* in_sizes, int n_in,
                              void* d_out, int out_size, void* d_ws, size_t ws_size,
                              hipStream_t stream) {
  const int* ei = (const int*)d_in[1];
  const int N = in_sizes[0] / CD;
  const int E = in_sizes[1] / 2;
  const size_t NC = (size_t)N * CD;
  const int nB = (N + 255) / 256;
  int shift = 0;
  while (((N - 1) >> shift) >= 256) shift++;  // 256 coarse buckets

  float* p = (float*)d_ws;
  float* hbuf = p;                                    // NC f32
  float* qbuf = p + NC;                               // NC f32
  float* cur = p + 2 * NC;
  unsigned short* hbuf16 = (unsigned short*)cur; cur += NC / 2;
  unsigned short* kbuf16 = (unsigned short*)cur; cur += NC / 2;
  unsigned short* vbuf16 = (unsigned short*)cur; cur += NC / 2;
  unsigned short* agg16 = (unsigned short*)cur; cur += NC / 2;
  int* ip = (int*)cur;
  int* deg = ip;
  int* tmp = ip + N;
  int* rowptr = ip + 2 * N;
  int* fill = ip + 3 * N;
  int* bsum = ip + 4 * N;
  int* csr_src = ip + 4 * N + nB;
  int* bcnt = csr_src + E;     // 256
  int* bbase = bcnt + 256;     // 256
  int* bfill = bbase + 256;    // 256
  cur = (float*)(bfill + 256);
  unsigned short* wkeT = (unsigned short*)cur; cur += (size_t)LL * CD * CD / 2;
  unsigned short* wveT = (unsigned short*)cur; cur += (size_t)LL * CD * CD / 2;
  unsigned short* wqT = (unsigned short*)cur; cur += (size_t)LL * CD * CD / 2;
  unsigned short* waT = (unsigned short*)cur; cur += (size_t)LL * CD * CD / 2;
  float* bke = cur; cur += (size_t)LL * CD;
  float* bve = cur; cur += (size_t)LL * CD;
  float* pblock = cur;
  float* pWk = cur; cur += (size_t)LL * CD * CD;
  float* pbk = cur; cur += (size_t)LL * CD;
  float* pWq = cur; cur += (size_t)LL * CD * CD;
  float* pbq = cur; cur += (size_t)LL * CD;
  float* pWv = cur; cur += (size_t)LL * CD * CD;
  float* pbv = cur; cur += (size_t)LL * CD;
  float* par = cur; cur += (size_t)LL * HH * DH * DH;
  float* pmr = cur; cur += (size_t)LL * HH * DH * DH;
  float* ppr = cur; cur += (size_t)LL * HH;
  float* pWa = cur; cur += (size_t)LL * CD * CD;
  float* pba = cur; cur += (size_t)LL * CD;
  float* pskip = cur; cur += LL;
  float* pWfc = cur; cur += (size_t)CD * 2;
  float* pbfc = cur; cur += 2;
  int* flags = (int*)cur;

  // binned-edge staging aliases kbuf16/vbuf16 (only used before layer loop)
  int* ebs = (int*)kbuf16;       // E ints
  int* ebd = ebs + E;            // E ints

  k_detect<<<1, 128, 0, stream>>>(d_in[0], ei, flags);
  k_cvt_x<<<((int)NC + 255) / 256, 256, 0, stream>>>(d_in[0], hbuf, hbuf16,
                                                     (int)NC, flags);

  SegTab tab;
  const int sizes[NSEG] = {LL * CD * CD, LL * CD, LL * CD * CD, LL * CD,
                           LL * CD * CD, LL * CD, LL * HH * DH * DH,
                           LL * HH * DH * DH, LL * HH, LL * CD * CD, LL * CD,
                           LL, CD * 2, 2};
  const int srcIdx[NSEG] = {2, 3, 4, 5, 6, 7, 8, 9, 10, 11, 12, 13, 14, 15};
  int off = 0;
  for (int k = 0; k < NSEG; k++) {
    tab.src[k] = d_in[srcIdx[k]];
    tab.off[k] = off;
    off += sizes[k];
  }
  tab.total = off;
  k_cvt_params<<<(off + 255) / 256, 256, 0, stream>>>(tab, pblock, flags);

  k_eff<<<dim3(CD + 1, HH, LL * 2), DH, 0, stream>>>(pWk, pbk, pWv, pbv, par, pmr,
                                                     wkeT, bke, wveT, bve);
  k_wt<<<dim3(CD, 2 * LL), CD, 0, stream>>>(pWq, pWa, wqT, waT);

  // ---- CSR build with multisplit ----
  hipMemsetAsync(deg, 0, (size_t)N * sizeof(int), stream);
  hipMemsetAsync(bcnt, 0, 256 * sizeof(int), stream);
  k_hist<<<(E + 255) / 256, 256, 0, stream>>>(ei, deg, flags, E, N);
  k_bcount<<<(E + BTILE - 1) / BTILE, 256, 0, stream>>>(ei, bcnt, flags, E, N, shift);
  k_scan1<<<nB, 256, 0, stream>>>(deg, tmp, bsum, N);
  k_scan2<<<1, 256, 0, stream>>>(bsum, nB);
  k_scan3<<<nB, 256, 0, stream>>>(tmp, deg, bsum, rowptr, fill, N);
  k_bscan<<<1, 256, 0, stream>>>(bcnt, bbase, bfill);
  k_bin<<<(E + BTILE - 1) / BTILE, 256, 0, stream>>>(ei, bfill, ebs, ebd, flags,
                                                     E, N, shift);
  k_scatter2<<<512, 256, 0, stream>>>(bbase, bcnt, ebs, ebd, fill, csr_src);

  const int mfmaBlocks = (N + 63) / 64;
  for (int l = 0; l < LL; l++) {
    k_gemm_mfma<0><<<mfmaBlocks, 256, 0, stream>>>(
        hbuf16, wqT + (size_t)l * CD * CD, pbq + (size_t)l * CD, qbuf,
        nullptr, nullptr, nullptr, N);
    k_gemm_mfma<1><<<mfmaBlocks, 256, 0, stream>>>(
        hbuf16, wkeT + (size_t)l * CD * CD, bke + (size_t)l * CD, kbuf16,
        nullptr, nullptr, nullptr, N);
    k_gemm_mfma<1><<<mfmaBlocks, 256, 0, stream>>>(
        hbuf16, wveT + (size_t)l * CD * CD, bve + (size_t)l * CD, vbuf16,
        nullptr, nullptr, nullptr, N);

    k_edge<<<(N + 3) / 4, 256, 0, stream>>>(qbuf, kbuf16, vbuf16, rowptr, deg,
                                            csr_src, ppr + (size_t)l * HH, agg16, N);

    // gelu(agg)@Wa + ba, gated residual -> hbuf (f32) + hbuf16 (bf16)
    k_gemm_mfma<2><<<mfmaBlocks, 256, 0, stream>>>(
        agg16, waT + (size_t)l * CD * CD, pba + (size_t)l * CD, nullptr,
        hbuf, hbuf16, pskip + l, N);
  }
  k_final<<<(N + 7) / 8, 256, 0, stream>>>(hbuf, pWfc, pbfc, d_out, flags, N);
}

// Round 14
// 838.213 us; speedup vs baseline: 2.0859x; 1.0412x over previous
//
#include <hip/hip_runtime.h>
#include <hip/hip_bf16.h>
#include <math.h>

#define CD 128
#define HH 4
#define DH 32
#define LL 2

using bf16 = __hip_bfloat16;
using bf16x8 = __attribute__((ext_vector_type(8))) short;  // 8 bf16 (4 VGPRs)
using f32x4 = __attribute__((ext_vector_type(4))) float;

__device__ __forceinline__ float bfbits2f(unsigned int s) {
  return __uint_as_float(s << 16);
}

__device__ __forceinline__ unsigned short f2bfbits(float f) {
  unsigned int u = __float_as_uint(f);
  unsigned int r = (u + 0x7fff + ((u >> 16) & 1)) >> 16;  // RNE
  return (unsigned short)r;
}

__device__ __forceinline__ float gelu_f(float x) {
  return 0.5f * x * (1.0f + erff(x * 0.70710678118654752f));
}

// ---- detect input formats: flags[0]=floats-are-f32, flags[1]=edge-index-is-i64 ----
__global__ void k_detect(const void* __restrict__ x, const int* __restrict__ ei,
                         int* __restrict__ flags) {
  __shared__ int cnt_f32, cnt_i32;
  if (threadIdx.x == 0) { cnt_f32 = 0; cnt_i32 = 0; }
  __syncthreads();
  int t = threadIdx.x;  // 128 threads
  unsigned short u = ((const unsigned short*)x)[2 * t];
  float v = bfbits2f((unsigned int)u);
  float av = fabsf(v);
  if (av != 0.f && (av > 1e8f || av < 1e-8f)) atomicAdd(&cnt_f32, 1);
  if (t < 64) {
    if (((const int*)ei)[2 * t + 1] != 0) atomicAdd(&cnt_i32, 1);
  }
  __syncthreads();
  if (threadIdx.x == 0) {
    flags[0] = (cnt_f32 > 8) ? 1 : 0;
    flags[1] = (cnt_i32 == 0) ? 1 : 0;
  }
}

// ---- x -> f32 hbuf AND bf16 hbuf16 ----
__global__ void k_cvt_x(const void* __restrict__ in, float* __restrict__ out,
                        unsigned short* __restrict__ out16, int n,
                        const int* __restrict__ flags) {
  int i = blockIdx.x * blockDim.x + threadIdx.x;
  if (i >= n) return;
  float v = flags[0] ? ((const float*)in)[i]
                     : bfbits2f((unsigned int)((const unsigned short*)in)[i]);
  out[i] = v;
  out16[i] = f2bfbits(v);
}

// ---- all parameter tensors -> contiguous f32 block, one launch ----
#define NSEG 14
struct SegTab {
  const void* src[NSEG];
  int off[NSEG];
  int total;
};
__global__ void k_cvt_params(SegTab tab, float* __restrict__ dst,
                             const int* __restrict__ flags) {
  int i = blockIdx.x * 256 + threadIdx.x;
  if (i >= tab.total) return;
  int seg = 0;
#pragma unroll
  for (int k = 1; k < NSEG; k++)
    if (i >= tab.off[k]) seg = k;
  int j = i - tab.off[seg];
  const void* src = tab.src[seg];
  dst[i] = flags[0] ? ((const float*)src)[j]
                    : bfbits2f((unsigned int)((const unsigned short*)src)[j]);
}

__device__ __forceinline__ int edge_idx(const int* __restrict__ ei, long pos, int is64) {
  return is64 ? ei[2 * pos] : ei[pos];
}

// ---- fold relation transforms into K/V weights: emit bf16 TRANSPOSED WT[n][k] ----
__global__ void k_eff(const float* __restrict__ Wk, const float* __restrict__ bk,
                      const float* __restrict__ Wv, const float* __restrict__ bv,
                      const float* __restrict__ ar, const float* __restrict__ mr,
                      unsigned short* __restrict__ wkeT, float* __restrict__ bke,
                      unsigned short* __restrict__ wveT, float* __restrict__ bve) {
  int c = blockIdx.x, h = blockIdx.y, z = blockIdx.z;
  int l = z >> 1, which = z & 1;
  int e = threadIdx.x;
  const float* W = (which ? Wv : Wk) + (size_t)l * CD * CD;
  const float* B = (which ? bv : bk) + (size_t)l * CD;
  const float* R = (which ? mr : ar) + (size_t)l * HH * DH * DH + h * DH * DH;
  unsigned short* WoT = (which ? wveT : wkeT) + (size_t)l * CD * CD;
  float* Bo = (which ? bve : bke) + (size_t)l * CD;
  float acc = 0.f;
  if (c < CD) {
#pragma unroll
    for (int d = 0; d < DH; d++) acc += W[c * CD + h * DH + d] * R[d * DH + e];
    WoT[(size_t)(h * DH + e) * CD + c] = f2bfbits(acc);  // transposed [n][k]
  } else {
#pragma unroll
    for (int d = 0; d < DH; d++) acc += B[h * DH + d] * R[d * DH + e];
    Bo[h * DH + e] = acc;
  }
}

// ---- transpose Wq/Wa to bf16 WT[n][k], both layers ----
__global__ void k_wt(const float* __restrict__ Wq, const float* __restrict__ Wa,
                     unsigned short* __restrict__ WqT, unsigned short* __restrict__ WaT) {
  int cout = blockIdx.x, z = blockIdx.y;
  int l = z >> 1, which = z & 1;
  int cin = threadIdx.x;
  const float* W = (which ? Wa : Wq) + (size_t)l * CD * CD;
  unsigned short* WT = (which ? WaT : WqT) + (size_t)l * CD * CD;
  WT[(size_t)cout * CD + cin] = f2bfbits(W[(size_t)cin * CD + cout]);
}

// ==== fused q/k/v MFMA GEMM, zero-LDS; grid.y selects projection.
// y=0: q (f32 out); y=1: k (bf16 out); y=2: v (bf16 out). ====
__global__ __launch_bounds__(256) void k_gemm_qkv(
    const unsigned short* __restrict__ A,
    const unsigned short* __restrict__ wq, const unsigned short* __restrict__ wk,
    const unsigned short* __restrict__ wv,
    const float* __restrict__ bq, const float* __restrict__ bk,
    const float* __restrict__ bv,
    float* __restrict__ qout, unsigned short* __restrict__ kout,
    unsigned short* __restrict__ vout, int nrows) {
  const int which = blockIdx.y;
  const unsigned short* BT = (which == 0) ? wq : (which == 1) ? wk : wv;
  const float* bias = (which == 0) ? bq : (which == 1) ? bk : bv;
  const int w = threadIdx.x >> 6;
  const int l = threadIdx.x & 63;
  const int r0 = blockIdx.x * 64 + w * 16;
  if (r0 >= nrows) return;
  const int lrow = l & 15;
  const int quad = l >> 4;
  const int k0 = quad * 8;

  f32x4 acc[8];
#pragma unroll
  for (int ct = 0; ct < 8; ct++) {
    float b = bias[ct * 16 + lrow];
    acc[ct] = (f32x4){b, b, b, b};
  }
  int ar = r0 + lrow;
  if (ar >= nrows) ar = nrows - 1;
  const unsigned short* Ap = A + (size_t)ar * CD;
#pragma unroll
  for (int kc = 0; kc < 4; kc++) {
    bf16x8 af = *(const bf16x8*)(Ap + kc * 32 + k0);
#pragma unroll
    for (int ct = 0; ct < 8; ct++) {
      bf16x8 bfr = *(const bf16x8*)(BT + (size_t)(ct * 16 + lrow) * CD + kc * 32 + k0);
      acc[ct] = __builtin_amdgcn_mfma_f32_16x16x32_bf16(af, bfr, acc[ct], 0, 0, 0);
    }
  }
#pragma unroll
  for (int ct = 0; ct < 8; ct++) {
#pragma unroll
    for (int i = 0; i < 4; i++) {
      int gr = r0 + quad * 4 + i;
      if (gr >= nrows) continue;
      int col = ct * 16 + lrow;
      float val = acc[ct][i];
      if (which == 0) {
        qout[(size_t)gr * CD + col] = val;
      } else {
        unsigned short* o = (which == 1) ? kout : vout;
        o[(size_t)gr * CD + col] = f2bfbits(val);
      }
    }
  }
}

// ==== gate MFMA GEMM: gelu(agg)@Wa + ba, gated residual -> h(f32) + h16(bf16) ====
__global__ __launch_bounds__(256) void k_gemm_gate(
    const unsigned short* __restrict__ A, const unsigned short* __restrict__ BT,
    const float* __restrict__ bias, float* __restrict__ h,
    unsigned short* __restrict__ h16, const float* __restrict__ skip, int nrows) {
  const int w = threadIdx.x >> 6;
  const int l = threadIdx.x & 63;
  const int r0 = blockIdx.x * 64 + w * 16;
  if (r0 >= nrows) return;
  const int lrow = l & 15;
  const int quad = l >> 4;
  const int k0 = quad * 8;

  f32x4 acc[8];
#pragma unroll
  for (int ct = 0; ct < 8; ct++) {
    float b = bias[ct * 16 + lrow];
    acc[ct] = (f32x4){b, b, b, b};
  }
  int ar = r0 + lrow;
  if (ar >= nrows) ar = nrows - 1;
  const unsigned short* Ap = A + (size_t)ar * CD;
#pragma unroll
  for (int kc = 0; kc < 4; kc++) {
    bf16x8 af = *(const bf16x8*)(Ap + kc * 32 + k0);
#pragma unroll
    for (int ct = 0; ct < 8; ct++) {
      bf16x8 bfr = *(const bf16x8*)(BT + (size_t)(ct * 16 + lrow) * CD + kc * 32 + k0);
      acc[ct] = __builtin_amdgcn_mfma_f32_16x16x32_bf16(af, bfr, acc[ct], 0, 0, 0);
    }
  }
  float gg = 1.f / (1.f + __expf(-skip[0]));
#pragma unroll
  for (int ct = 0; ct < 8; ct++) {
#pragma unroll
    for (int i = 0; i < 4; i++) {
      int gr = r0 + quad * 4 + i;
      if (gr >= nrows) continue;
      size_t ix = (size_t)gr * CD + ct * 16 + lrow;
      float o = gg * acc[ct][i] + (1.f - gg) * h[ix];
      h[ix] = o;
      h16[ix] = f2bfbits(o);
    }
  }
}

// ==== CSR build ====
#define BTILE 4096
// fused: per-node degree atomics + LDS-aggregated coarse-bucket histogram
__global__ __launch_bounds__(256) void k_histb(
    const int* __restrict__ ei, int* __restrict__ deg, int* __restrict__ bcnt,
    const int* __restrict__ flags, int E, int Nn, int shift) {
  __shared__ int cnt[256];
  cnt[threadIdx.x] = 0;
  __syncthreads();
  const int t0 = blockIdx.x * BTILE;
  const int is64 = flags[1];
  for (int j = 0; j < 16; j++) {
    int i = t0 + threadIdx.x + j * 256;
    if (i < E) {
      int d = edge_idx(ei, (long)E + i, is64);
      if ((unsigned)d >= (unsigned)Nn) d = 0;
      atomicAdd(&deg[d], 1);
      atomicAdd(&cnt[d >> shift], 1);
    }
  }
  __syncthreads();
  int v = cnt[threadIdx.x];
  if (v > 0) atomicAdd(&bcnt[threadIdx.x], v);
}

__global__ void k_scan1(const int* __restrict__ deg, int* __restrict__ tmp,
                        int* __restrict__ bsum, int n) {
  __shared__ int sh[256];
  int i = blockIdx.x * 256 + threadIdx.x;
  int v = (i < n) ? deg[i] : 0;
  sh[threadIdx.x] = v;
  __syncthreads();
  for (int off = 1; off < 256; off <<= 1) {
    int t = (threadIdx.x >= off) ? sh[threadIdx.x - off] : 0;
    __syncthreads();
    sh[threadIdx.x] += t;
    __syncthreads();
  }
  if (i < n) tmp[i] = sh[threadIdx.x];
  if (threadIdx.x == 255) bsum[blockIdx.x] = sh[255];
}

__global__ void k_scan2(int* __restrict__ bsum, int nb) {
  __shared__ int sh[256];
  __shared__ int carry;
  if (threadIdx.x == 0) carry = 0;
  __syncthreads();
  for (int base = 0; base < nb; base += 256) {
    int i = base + threadIdx.x;
    int v = (i < nb) ? bsum[i] : 0;
    sh[threadIdx.x] = v;
    __syncthreads();
    for (int off = 1; off < 256; off <<= 1) {
      int t = (threadIdx.x >= off) ? sh[threadIdx.x - off] : 0;
      __syncthreads();
      sh[threadIdx.x] += t;
      __syncthreads();
    }
    if (i < nb) bsum[i] = sh[threadIdx.x] + carry;
    __syncthreads();
    if (threadIdx.x == 0) carry += sh[255];
    __syncthreads();
  }
}

__global__ void k_scan3(const int* __restrict__ tmp, const int* __restrict__ deg,
                        const int* __restrict__ bsum, int* __restrict__ rowptr,
                        int* __restrict__ fill, int n) {
  int i = blockIdx.x * 256 + threadIdx.x;
  if (i >= n) return;
  int off = (blockIdx.x > 0) ? bsum[blockIdx.x - 1] : 0;
  int excl = tmp[i] - deg[i] + off;
  rowptr[i] = excl;
  fill[i] = excl;
}

// exclusive scan of 256 bucket counts -> bbase; also init bfill
__global__ void k_bscan(const int* __restrict__ bcnt, int* __restrict__ bbase,
                        int* __restrict__ bfill) {
  __shared__ int sh[256];
  int t = threadIdx.x;
  int v = bcnt[t];
  sh[t] = v;
  __syncthreads();
  for (int off = 1; off < 256; off <<= 1) {
    int u = (t >= off) ? sh[t - off] : 0;
    __syncthreads();
    sh[t] += u;
    __syncthreads();
  }
  int excl = sh[t] - v;
  bbase[t] = excl;
  bfill[t] = excl;
}

// bin 4096-edge tiles into coarse buckets with clustered global writes
__global__ __launch_bounds__(256) void k_bin(
    const int* __restrict__ ei, int* __restrict__ bfill,
    int* __restrict__ ebs, int* __restrict__ ebd,
    const int* __restrict__ flags, int E, int Nn, int shift) {
  __shared__ int sS[BTILE];
  __shared__ int sD[BTILE];
  __shared__ int cnt[256], pref[256], base[256], lofs[256];
  const int t = threadIdx.x;
  cnt[t] = 0;
  lofs[t] = 0;
  __syncthreads();
  const int t0 = blockIdx.x * BTILE;
  const int is64 = flags[1];
  for (int j = 0; j < 16; j++) {
    int i = t0 + t + j * 256;
    if (i < E) {
      int d = edge_idx(ei, (long)E + i, is64);
      if ((unsigned)d >= (unsigned)Nn) d = 0;
      atomicAdd(&cnt[d >> shift], 1);
    }
  }
  __syncthreads();
  {
    int v = cnt[t];
    pref[t] = v;
    __syncthreads();
    for (int off = 1; off < 256; off <<= 1) {
      int u = (t >= off) ? pref[t - off] : 0;
      __syncthreads();
      pref[t] += u;
      __syncthreads();
    }
    int incl = pref[t];
    __syncthreads();
    pref[t] = incl - v;
    base[t] = (v > 0) ? atomicAdd(&bfill[t], v) : 0;
  }
  __syncthreads();
  for (int j = 0; j < 16; j++) {
    int i = t0 + t + j * 256;
    if (i < E) {
      int s = edge_idx(ei, (long)i, is64);
      int d = edge_idx(ei, (long)E + i, is64);
      if ((unsigned)s >= (unsigned)Nn) s = 0;
      if ((unsigned)d >= (unsigned)Nn) d = 0;
      int b = d >> shift;
      int p = pref[b] + atomicAdd(&lofs[b], 1);
      sS[p] = s;
      sD[p] = d;
    }
  }
  __syncthreads();
  int tot = E - t0;
  if (tot > BTILE) tot = BTILE;
  for (int j = 0; j < 16; j++) {
    int i = t + j * 256;
    if (i < tot) {
      int d = sD[i];
      int b = d >> shift;
      int gp = base[b] + (i - pref[b]);
      ebs[gp] = sS[i];
      ebd[gp] = d;
    }
  }
}

// final scatter within per-bucket csr window (L2-local)
__global__ void k_scatter2(const int* __restrict__ bbase, const int* __restrict__ bcnt,
                           const int* __restrict__ ebs, const int* __restrict__ ebd,
                           int* __restrict__ fill, int* __restrict__ csr_src) {
  int b = blockIdx.x >> 1, half = blockIdx.x & 1;
  int s0 = bbase[b], c = bcnt[b];
  int st = s0 + (half ? (c + 1) / 2 : 0);
  int en = s0 + (half ? c : (c + 1) / 2);
  for (int i = st + threadIdx.x; i < en; i += 256) {
    int s = ebs[i], d = ebd[i];
    int pos = atomicAdd(&fill[d], 1);
    csr_src[pos] = s;
  }
}

// ==== fused attention, k/v bf16, NO online-max (logits are O(sigma)~1; clamped).
// 1 wave/node; 4 edge-slots x 16 lanes; lane j: dims 8j..8j+7 (head j>>2).
// p_rel/sqrt(D) folded into q. Epilogue: GELU + bf16 pack. ====
__global__ __launch_bounds__(256) void k_edge(
    const float* __restrict__ q, const unsigned short* __restrict__ kk,
    const unsigned short* __restrict__ v, const int* __restrict__ rowptr,
    const int* __restrict__ deg, const int* __restrict__ csr_src,
    const float* __restrict__ p_rel, unsigned short* __restrict__ agg16, int N) {
  int n = (blockIdx.x * 256 + threadIdx.x) >> 6;
  if (n >= N) return;
  const int lane = threadIdx.x & 63;
  const int g = lane >> 4;
  const int j = lane & 15;
  const int start = rowptr[n];
  const int end = start + deg[n];
  const float prl = p_rel[j >> 2] * 0.17677669529663687f;  // 1/sqrt(32)
  float4 qa = *(const float4*)(q + (size_t)n * CD + 8 * j);
  float4 qb = *(const float4*)(q + (size_t)n * CD + 8 * j + 4);
  qa.x *= prl; qa.y *= prl; qa.z *= prl; qa.w *= prl;
  qb.x *= prl; qb.y *= prl; qb.z *= prl; qb.w *= prl;
  float den = 0.f;
  float acc[8] = {0.f, 0.f, 0.f, 0.f, 0.f, 0.f, 0.f, 0.f};
  for (int e = start + g; e < end; e += 4) {
    int s = csr_src[e];
    uint4 ku = *(const uint4*)(kk + (size_t)s * CD + 8 * j);  // 8 bf16 = 16 B
    uint4 vu = *(const uint4*)(v + (size_t)s * CD + 8 * j);
    float k0 = bfbits2f(ku.x & 0xffffu), k1 = bfbits2f(ku.x >> 16);
    float k2 = bfbits2f(ku.y & 0xffffu), k3 = bfbits2f(ku.y >> 16);
    float k4 = bfbits2f(ku.z & 0xffffu), k5 = bfbits2f(ku.z >> 16);
    float k6 = bfbits2f(ku.w & 0xffffu), k7 = bfbits2f(ku.w >> 16);
    float v0 = bfbits2f(vu.x & 0xffffu), v1 = bfbits2f(vu.x >> 16);
    float v2 = bfbits2f(vu.y & 0xffffu), v3 = bfbits2f(vu.y >> 16);
    float v4 = bfbits2f(vu.z & 0xffffu), v5 = bfbits2f(vu.z >> 16);
    float v6 = bfbits2f(vu.w & 0xffffu), v7 = bfbits2f(vu.w >> 16);
    float pd = qa.x * k0 + qa.y * k1 + qa.z * k2 + qa.w * k3 +
               qb.x * k4 + qb.y * k5 + qb.z * k6 + qb.w * k7;
    pd += __shfl_xor(pd, 1);
    pd += __shfl_xor(pd, 2);
    float ew = __expf(fminf(pd, 60.f));  // no max-sub: |logit| ~ O(1), safe
    acc[0] += ew * v0; acc[1] += ew * v1;
    acc[2] += ew * v2; acc[3] += ew * v3;
    acc[4] += ew * v4; acc[5] += ew * v5;
    acc[6] += ew * v6; acc[7] += ew * v7;
    den += ew;
  }
#pragma unroll
  for (int off = 16; off <= 32; off <<= 1) {
    den += __shfl_xor(den, off);
#pragma unroll
    for (int i = 0; i < 8; i++) acc[i] += __shfl_xor(acc[i], off);
  }
  if (g == 0) {
    float inv = (den > 0.f) ? 1.f / den : 0.f;
    ushort4 o0, o1;
    o0.x = f2bfbits(gelu_f(acc[0] * inv)); o0.y = f2bfbits(gelu_f(acc[1] * inv));
    o0.z = f2bfbits(gelu_f(acc[2] * inv)); o0.w = f2bfbits(gelu_f(acc[3] * inv));
    o1.x = f2bfbits(gelu_f(acc[4] * inv)); o1.y = f2bfbits(gelu_f(acc[5] * inv));
    o1.z = f2bfbits(gelu_f(acc[6] * inv)); o1.w = f2bfbits(gelu_f(acc[7] * inv));
    *(ushort4*)(agg16 + (size_t)n * CD + 8 * j) = o0;
    *(ushort4*)(agg16 + (size_t)n * CD + 8 * j + 4) = o1;
  }
}

// ---- out[n,0:2] = h[n,:] @ Wfc + bfc; f32 out if flags[0] else bf16 ----
__global__ __launch_bounds__(256) void k_final(const float* __restrict__ h,
                                               const float* __restrict__ Wfc,
                                               const float* __restrict__ bfc,
                                               void* __restrict__ out,
                                               const int* __restrict__ flags, int N) {
  int g = (blockIdx.x * 256 + threadIdx.x) >> 5;
  int lane = threadIdx.x & 31;
  if (g >= N) return;
  const float* hr = h + (size_t)g * CD;
  float a0 = 0.f, a1 = 0.f;
#pragma unroll
  for (int j = 0; j < 4; j++) {
    float hv = hr[lane + 32 * j];
    a0 += hv * Wfc[(lane + 32 * j) * 2];
    a1 += hv * Wfc[(lane + 32 * j) * 2 + 1];
  }
#pragma unroll
  for (int off = 16; off; off >>= 1) {
    a0 += __shfl_xor(a0, off);
    a1 += __shfl_xor(a1, off);
  }
  if (lane == 0) {
    float o0 = a0 + bfc[0];
    float o1 = a1 + bfc[1];
    if (flags[0]) {
      ((float*)out)[(size_t)g * 2] = o0;
      ((float*)out)[(size_t)g * 2 + 1] = o1;
    } else {
      ((bf16*)out)[(size_t)g * 2] = __float2bfloat16(o0);
      ((bf16*)out)[(size_t)g * 2 + 1] = __float2bfloat16(o1);
    }
  }
}

extern "C" void kernel_launch(void* const* d_in, const int* in_sizes, int n_in,
                              void* d_out, int out_size, void* d_ws, size_t ws_size,
                              hipStream_t stream) {
  const int* ei = (const int*)d_in[1];
  const int N = in_sizes[0] / CD;
  const int E = in_sizes[1] / 2;
  const size_t NC = (size_t)N * CD;
  const int nB = (N + 255) / 256;
  int shift = 0;
  while (((N - 1) >> shift) >= 256) shift++;  // 256 coarse buckets

  float* p = (float*)d_ws;
  float* hbuf = p;                                    // NC f32
  float* qbuf = p + NC;                               // NC f32
  float* cur = p + 2 * NC;
  unsigned short* hbuf16 = (unsigned short*)cur; cur += NC / 2;
  unsigned short* kbuf16 = (unsigned short*)cur; cur += NC / 2;
  unsigned short* vbuf16 = (unsigned short*)cur; cur += NC / 2;
  unsigned short* agg16 = (unsigned short*)cur; cur += NC / 2;
  int* ip = (int*)cur;
  int* deg = ip;
  int* tmp = ip + N;
  int* rowptr = ip + 2 * N;
  int* fill = ip + 3 * N;
  int* bsum = ip + 4 * N;
  int* csr_src = ip + 4 * N + nB;
  int* bcnt = csr_src + E;     // 256
  int* bbase = bcnt + 256;     // 256
  int* bfill = bbase + 256;    // 256
  cur = (float*)(bfill + 256);
  unsigned short* wkeT = (unsigned short*)cur; cur += (size_t)LL * CD * CD / 2;
  unsigned short* wveT = (unsigned short*)cur; cur += (size_t)LL * CD * CD / 2;
  unsigned short* wqT = (unsigned short*)cur; cur += (size_t)LL * CD * CD / 2;
  unsigned short* waT = (unsigned short*)cur; cur += (size_t)LL * CD * CD / 2;
  float* bke = cur; cur += (size_t)LL * CD;
  float* bve = cur; cur += (size_t)LL * CD;
  float* pblock = cur;
  float* pWk = cur; cur += (size_t)LL * CD * CD;
  float* pbk = cur; cur += (size_t)LL * CD;
  float* pWq = cur; cur += (size_t)LL * CD * CD;
  float* pbq = cur; cur += (size_t)LL * CD;
  float* pWv = cur; cur += (size_t)LL * CD * CD;
  float* pbv = cur; cur += (size_t)LL * CD;
  float* par = cur; cur += (size_t)LL * HH * DH * DH;
  float* pmr = cur; cur += (size_t)LL * HH * DH * DH;
  float* ppr = cur; cur += (size_t)LL * HH;
  float* pWa = cur; cur += (size_t)LL * CD * CD;
  float* pba = cur; cur += (size_t)LL * CD;
  float* pskip = cur; cur += LL;
  float* pWfc = cur; cur += (size_t)CD * 2;
  float* pbfc = cur; cur += 2;
  int* flags = (int*)cur;

  // binned-edge staging aliases kbuf16/vbuf16 (only used before layer loop)
  int* ebs = (int*)kbuf16;       // E ints
  int* ebd = ebs + E;            // E ints

  k_detect<<<1, 128, 0, stream>>>(d_in[0], ei, flags);
  k_cvt_x<<<((int)NC + 255) / 256, 256, 0, stream>>>(d_in[0], hbuf, hbuf16,
                                                     (int)NC, flags);

  SegTab tab;
  const int sizes[NSEG] = {LL * CD * CD, LL * CD, LL * CD * CD, LL * CD,
                           LL * CD * CD, LL * CD, LL * HH * DH * DH,
                           LL * HH * DH * DH, LL * HH, LL * CD * CD, LL * CD,
                           LL, CD * 2, 2};
  const int srcIdx[NSEG] = {2, 3, 4, 5, 6, 7, 8, 9, 10, 11, 12, 13, 14, 15};
  int off = 0;
  for (int k = 0; k < NSEG; k++) {
    tab.src[k] = d_in[srcIdx[k]];
    tab.off[k] = off;
    off += sizes[k];
  }
  tab.total = off;
  k_cvt_params<<<(off + 255) / 256, 256, 0, stream>>>(tab, pblock, flags);

  k_eff<<<dim3(CD + 1, HH, LL * 2), DH, 0, stream>>>(pWk, pbk, pWv, pbv, par, pmr,
                                                     wkeT, bke, wveT, bve);
  k_wt<<<dim3(CD, 2 * LL), CD, 0, stream>>>(pWq, pWa, wqT, waT);

  // ---- CSR build with multisplit ----
  hipMemsetAsync(deg, 0, (size_t)N * sizeof(int), stream);
  hipMemsetAsync(bcnt, 0, 256 * sizeof(int), stream);
  k_histb<<<(E + BTILE - 1) / BTILE, 256, 0, stream>>>(ei, deg, bcnt, flags, E, N, shift);
  k_scan1<<<nB, 256, 0, stream>>>(deg, tmp, bsum, N);
  k_scan2<<<1, 256, 0, stream>>>(bsum, nB);
  k_scan3<<<nB, 256, 0, stream>>>(tmp, deg, bsum, rowptr, fill, N);
  k_bscan<<<1, 256, 0, stream>>>(bcnt, bbase, bfill);
  k_bin<<<(E + BTILE - 1) / BTILE, 256, 0, stream>>>(ei, bfill, ebs, ebd, flags,
                                                     E, N, shift);
  k_scatter2<<<512, 256, 0, stream>>>(bbase, bcnt, ebs, ebd, fill, csr_src);

  const int mfmaBlocks = (N + 63) / 64;
  for (int l = 0; l < LL; l++) {
    k_gemm_qkv<<<dim3(mfmaBlocks, 3), 256, 0, stream>>>(
        hbuf16,
        wqT + (size_t)l * CD * CD, wkeT + (size_t)l * CD * CD,
        wveT + (size_t)l * CD * CD,
        pbq + (size_t)l * CD, bke + (size_t)l * CD, bve + (size_t)l * CD,
        qbuf, kbuf16, vbuf16, N);

    k_edge<<<(N + 3) / 4, 256, 0, stream>>>(qbuf, kbuf16, vbuf16, rowptr, deg,
                                            csr_src, ppr + (size_t)l * HH, agg16, N);

    k_gemm_gate<<<mfmaBlocks, 256, 0, stream>>>(
        agg16, waT + (size_t)l * CD * CD, pba + (size_t)l * CD,
        hbuf, hbuf16, pskip + l, N);
  }
  k_final<<<(N + 7) / 8, 256, 0, stream>>>(hbuf, pWfc, pbfc, d_out, flags, N);
}